// Round 6
// baseline (404.530 us; speedup 1.0000x reference)
//
#include <hip/hip_runtime.h>

// GlobalFilter: y = irfft2(rfft2(x, ortho) * W, ortho)  ==  per-channel 14x14
// circular convolution with kernel R_c = (1/196) * Re(IFFT2(Wext_c)).
//
// x: (256, 196, 512) fp32, W: (14, 8, 512, 2) fp32, out: (256, 196, 512) fp32.
//
// ws layout: R  at offset 0            : 196*512 floats  (401,408 B)
//               *** pair layout ***: R[((dm*7 + dn/2)*512 + c)*2 + (dn&1)]
//            T  at offset 196*512      : 14*14*512*2 floats (802,816 B)
//
// Round-6: software-pipelined double-banked asm inner loop. R5 proved the
// stall is lockstep LDS bursts (all waves: reads -> waitcnt(0) -> FMAs, VALU
// idle during the whole burst). Now each p-block drains the PREVIOUS loads,
// issues NEXT loads into the other register bank, then FMAs — loads always
// land under the 392-cycle FMA phase.
//   banks: xA v40-67, xB v68-95, R_A v96-109, R_B v112-125 (b128-aligned)
//   acc + temps live in v0-39 / v110-111 / v126-127; launch_bounds caps 128.

#define Hs 14
#define Ns 196          // 14*14
#define Cc 512
#define CT 32           // channel tile
#define CONV_THREADS 448

typedef float v2f __attribute__((ext_vector_type(2)));

// ---------------------------------------------------------------------------
// Prep stage A (unchanged)
// ---------------------------------------------------------------------------
__global__ __launch_bounds__(256) void prep_a_kernel(const float* __restrict__ cw,
                                                     float* __restrict__ T) {
    __shared__ float cs[14], sn[14];
    if (threadIdx.x < 14) {
        float ang = (float)threadIdx.x * 0.44879895051282760549f;  // 2*pi/14
        cs[threadIdx.x] = cosf(ang);
        sn[threadIdx.x] = sinf(ang);
    }
    __syncthreads();

    int gid = blockIdx.x * 256 + threadIdx.x;   // 14*14*512
    int c = gid & 511;
    int s = gid >> 9;          // h*14 + dn
    int h = s / 14;
    int dn = s % 14;
    int h2 = (h == 0) ? 0 : (14 - h);

    float Tr = 0.0f, Ti = 0.0f;
    int k = 0;
    #pragma unroll
    for (int w = 0; w < 8; ++w) {
        const float* p = cw + (size_t)(((h * 8 + w) * 512 + c) * 2);
        float Wr = p[0], Wi = p[1];
        Tr += Wr * cs[k] - Wi * sn[k];
        Ti += Wr * sn[k] + Wi * cs[k];
        k += dn; if (k >= 14) k -= 14;
    }
    int k2 = dn; if (k2 >= 14) k2 -= 14;
    #pragma unroll
    for (int w = 1; w < 7; ++w) {
        const float* p = cw + (size_t)(((h2 * 8 + w) * 512 + c) * 2);
        float Wr = p[0], Wi = p[1];
        Tr += Wr * cs[k2] - Wi * sn[k2];
        Ti -= Wr * sn[k2] + Wi * cs[k2];
        k2 += dn; if (k2 >= 14) k2 -= 14;
    }
    float* o = T + (size_t)(s * 512 + c) * 2;
    o[0] = Tr;
    o[1] = Ti;
}

// ---------------------------------------------------------------------------
// Prep stage B (unchanged; writes R in dn-PAIR layout)
// ---------------------------------------------------------------------------
__global__ __launch_bounds__(256) void prep_b_kernel(const float* __restrict__ T,
                                                     float* __restrict__ R) {
    __shared__ float cs[14], sn[14];
    if (threadIdx.x < 14) {
        float ang = (float)threadIdx.x * 0.44879895051282760549f;  // 2*pi/14
        cs[threadIdx.x] = cosf(ang);
        sn[threadIdx.x] = sinf(ang);
    }
    __syncthreads();

    int gid = blockIdx.x * 256 + threadIdx.x;   // 196*512
    int c = gid & 511;
    int s = gid >> 9;          // dm*14 + dn
    int dm = s / 14;
    int dn = s % 14;

    float acc = 0.0f;
    int kh = 0;
    #pragma unroll
    for (int h = 0; h < 14; ++h) {
        const float* p = T + (size_t)(((h * 14 + dn) * 512 + c) * 2);
        acc += p[0] * cs[kh] - p[1] * sn[kh];
        kh += dm; if (kh >= 14) kh -= 14;
    }
    R[(size_t)(((dm * 7 + (dn >> 1)) * 512 + c) * 2 + (dn & 1))] = acc * (1.0f / 196.0f);
}

// ---------------------------------------------------------------------------
// Conv kernel (pipelined).  Per p-block:
//   s_waitcnt lgkmcnt(0)      (previous bank's 11 loads now complete)
//   11 ds_read (7 b128 x-row, 3 b128 + 1 b64 R-row) into the OTHER bank
//   196 v_pk_fma_f32 on the current bank (op_sel half-broadcast of R)
// FMA mapping (verified R2/R5): acc[(q+dn)%14] += x[q] * r[dn],
//   dn even -> pair.lo both lanes, dn odd -> pair.hi both lanes.
// ---------------------------------------------------------------------------
#define SEL_E "op_sel:[0,0,0] op_sel_hi:[1,0,1]"
#define SEL_O "op_sel:[0,1,0] op_sel_hi:[1,1,1]"

#define DIAG_A(R, S, a0,a1,a2,a3,a4,a5,a6,a7,a8,a9,aA,aB,aC,aD) \
  "v_pk_fma_f32 %" #a0 ", v[40:41], " R ", %" #a0 " " S "\n\t" \
  "v_pk_fma_f32 %" #a1 ", v[42:43], " R ", %" #a1 " " S "\n\t" \
  "v_pk_fma_f32 %" #a2 ", v[44:45], " R ", %" #a2 " " S "\n\t" \
  "v_pk_fma_f32 %" #a3 ", v[46:47], " R ", %" #a3 " " S "\n\t" \
  "v_pk_fma_f32 %" #a4 ", v[48:49], " R ", %" #a4 " " S "\n\t" \
  "v_pk_fma_f32 %" #a5 ", v[50:51], " R ", %" #a5 " " S "\n\t" \
  "v_pk_fma_f32 %" #a6 ", v[52:53], " R ", %" #a6 " " S "\n\t" \
  "v_pk_fma_f32 %" #a7 ", v[54:55], " R ", %" #a7 " " S "\n\t" \
  "v_pk_fma_f32 %" #a8 ", v[56:57], " R ", %" #a8 " " S "\n\t" \
  "v_pk_fma_f32 %" #a9 ", v[58:59], " R ", %" #a9 " " S "\n\t" \
  "v_pk_fma_f32 %" #aA ", v[60:61], " R ", %" #aA " " S "\n\t" \
  "v_pk_fma_f32 %" #aB ", v[62:63], " R ", %" #aB " " S "\n\t" \
  "v_pk_fma_f32 %" #aC ", v[64:65], " R ", %" #aC " " S "\n\t" \
  "v_pk_fma_f32 %" #aD ", v[66:67], " R ", %" #aD " " S "\n\t"

#define DIAG_B(R, S, a0,a1,a2,a3,a4,a5,a6,a7,a8,a9,aA,aB,aC,aD) \
  "v_pk_fma_f32 %" #a0 ", v[68:69], " R ", %" #a0 " " S "\n\t" \
  "v_pk_fma_f32 %" #a1 ", v[70:71], " R ", %" #a1 " " S "\n\t" \
  "v_pk_fma_f32 %" #a2 ", v[72:73], " R ", %" #a2 " " S "\n\t" \
  "v_pk_fma_f32 %" #a3 ", v[74:75], " R ", %" #a3 " " S "\n\t" \
  "v_pk_fma_f32 %" #a4 ", v[76:77], " R ", %" #a4 " " S "\n\t" \
  "v_pk_fma_f32 %" #a5 ", v[78:79], " R ", %" #a5 " " S "\n\t" \
  "v_pk_fma_f32 %" #a6 ", v[80:81], " R ", %" #a6 " " S "\n\t" \
  "v_pk_fma_f32 %" #a7 ", v[82:83], " R ", %" #a7 " " S "\n\t" \
  "v_pk_fma_f32 %" #a8 ", v[84:85], " R ", %" #a8 " " S "\n\t" \
  "v_pk_fma_f32 %" #a9 ", v[86:87], " R ", %" #a9 " " S "\n\t" \
  "v_pk_fma_f32 %" #aA ", v[88:89], " R ", %" #aA " " S "\n\t" \
  "v_pk_fma_f32 %" #aB ", v[90:91], " R ", %" #aB " " S "\n\t" \
  "v_pk_fma_f32 %" #aC ", v[92:93], " R ", %" #aC " " S "\n\t" \
  "v_pk_fma_f32 %" #aD ", v[94:95], " R ", %" #aD " " S "\n\t"

// full FMA section for a bank (14 diagonals, R pairs j=0..6, even/odd halves)
#define FMAS_A \
  DIAG_A("v[96:97]",   SEL_E,  0,1,2,3,4,5,6,7,8,9,10,11,12,13) \
  DIAG_A("v[96:97]",   SEL_O,  1,2,3,4,5,6,7,8,9,10,11,12,13,0) \
  DIAG_A("v[98:99]",   SEL_E,  2,3,4,5,6,7,8,9,10,11,12,13,0,1) \
  DIAG_A("v[98:99]",   SEL_O,  3,4,5,6,7,8,9,10,11,12,13,0,1,2) \
  DIAG_A("v[100:101]", SEL_E,  4,5,6,7,8,9,10,11,12,13,0,1,2,3) \
  DIAG_A("v[100:101]", SEL_O,  5,6,7,8,9,10,11,12,13,0,1,2,3,4) \
  DIAG_A("v[102:103]", SEL_E,  6,7,8,9,10,11,12,13,0,1,2,3,4,5) \
  DIAG_A("v[102:103]", SEL_O,  7,8,9,10,11,12,13,0,1,2,3,4,5,6) \
  DIAG_A("v[104:105]", SEL_E,  8,9,10,11,12,13,0,1,2,3,4,5,6,7) \
  DIAG_A("v[104:105]", SEL_O,  9,10,11,12,13,0,1,2,3,4,5,6,7,8) \
  DIAG_A("v[106:107]", SEL_E,  10,11,12,13,0,1,2,3,4,5,6,7,8,9) \
  DIAG_A("v[106:107]", SEL_O,  11,12,13,0,1,2,3,4,5,6,7,8,9,10) \
  DIAG_A("v[108:109]", SEL_E,  12,13,0,1,2,3,4,5,6,7,8,9,10,11) \
  DIAG_A("v[108:109]", SEL_O,  13,0,1,2,3,4,5,6,7,8,9,10,11,12)

#define FMAS_B \
  DIAG_B("v[112:113]", SEL_E,  0,1,2,3,4,5,6,7,8,9,10,11,12,13) \
  DIAG_B("v[112:113]", SEL_O,  1,2,3,4,5,6,7,8,9,10,11,12,13,0) \
  DIAG_B("v[114:115]", SEL_E,  2,3,4,5,6,7,8,9,10,11,12,13,0,1) \
  DIAG_B("v[114:115]", SEL_O,  3,4,5,6,7,8,9,10,11,12,13,0,1,2) \
  DIAG_B("v[116:117]", SEL_E,  4,5,6,7,8,9,10,11,12,13,0,1,2,3) \
  DIAG_B("v[116:117]", SEL_O,  5,6,7,8,9,10,11,12,13,0,1,2,3,4) \
  DIAG_B("v[118:119]", SEL_E,  6,7,8,9,10,11,12,13,0,1,2,3,4,5) \
  DIAG_B("v[118:119]", SEL_O,  7,8,9,10,11,12,13,0,1,2,3,4,5,6) \
  DIAG_B("v[120:121]", SEL_E,  8,9,10,11,12,13,0,1,2,3,4,5,6,7) \
  DIAG_B("v[120:121]", SEL_O,  9,10,11,12,13,0,1,2,3,4,5,6,7,8) \
  DIAG_B("v[122:123]", SEL_E,  10,11,12,13,0,1,2,3,4,5,6,7,8,9) \
  DIAG_B("v[122:123]", SEL_O,  11,12,13,0,1,2,3,4,5,6,7,8,9,10) \
  DIAG_B("v[124:125]", SEL_E,  12,13,0,1,2,3,4,5,6,7,8,9,10,11) \
  DIAG_B("v[124:125]", SEL_O,  13,0,1,2,3,4,5,6,7,8,9,10,11,12)

// loads into bank A (x -> v40-67, R -> v96-109); %x = x addr, %r = R addr
#define LOADS_TO_A(X, RA) \
  "ds_read_b128 v[40:43], " X "\n\t" \
  "ds_read_b128 v[44:47], " X " offset:16\n\t" \
  "ds_read_b128 v[48:51], " X " offset:32\n\t" \
  "ds_read_b128 v[52:55], " X " offset:48\n\t" \
  "ds_read_b128 v[56:59], " X " offset:64\n\t" \
  "ds_read_b128 v[60:63], " X " offset:80\n\t" \
  "ds_read_b128 v[64:67], " X " offset:96\n\t" \
  "ds_read_b128 v[96:99], " RA "\n\t" \
  "ds_read_b128 v[100:103], " RA " offset:16\n\t" \
  "ds_read_b128 v[104:107], " RA " offset:32\n\t" \
  "ds_read_b64  v[108:109], " RA " offset:48\n\t"

#define LOADS_TO_B(X, RA) \
  "ds_read_b128 v[68:71], " X "\n\t" \
  "ds_read_b128 v[72:75], " X " offset:16\n\t" \
  "ds_read_b128 v[76:79], " X " offset:32\n\t" \
  "ds_read_b128 v[80:83], " X " offset:48\n\t" \
  "ds_read_b128 v[84:87], " X " offset:64\n\t" \
  "ds_read_b128 v[88:91], " X " offset:80\n\t" \
  "ds_read_b128 v[92:95], " X " offset:96\n\t" \
  "ds_read_b128 v[112:115], " RA "\n\t" \
  "ds_read_b128 v[116:119], " RA " offset:16\n\t" \
  "ds_read_b128 v[120:123], " RA " offset:32\n\t" \
  "ds_read_b64  v[124:125], " RA " offset:48\n\t"

#define CLOB \
  "v40","v41","v42","v43","v44","v45","v46","v47", \
  "v48","v49","v50","v51","v52","v53","v54","v55", \
  "v56","v57","v58","v59","v60","v61","v62","v63", \
  "v64","v65","v66","v67","v68","v69","v70","v71", \
  "v72","v73","v74","v75","v76","v77","v78","v79", \
  "v80","v81","v82","v83","v84","v85","v86","v87", \
  "v88","v89","v90","v91","v92","v93","v94","v95", \
  "v96","v97","v98","v99","v100","v101","v102","v103", \
  "v104","v105","v106","v107","v108","v109", \
  "v112","v113","v114","v115","v116","v117","v118","v119", \
  "v120","v121","v122","v123","v124","v125"

#define ACCS \
  "+v"(acc[0]), "+v"(acc[1]), "+v"(acc[2]), "+v"(acc[3]), \
  "+v"(acc[4]), "+v"(acc[5]), "+v"(acc[6]), "+v"(acc[7]), \
  "+v"(acc[8]), "+v"(acc[9]), "+v"(acc[10]), "+v"(acc[11]), \
  "+v"(acc[12]), "+v"(acc[13])

#define XSTRIDE 199   // v2f units, c-major row stride for xs
#define RSTRIDE 99    // v2f units, c-major row stride for rs

__global__ __launch_bounds__(CONV_THREADS, 4) void conv_kernel(
        const float* __restrict__ x,
        const float* __restrict__ R,
        float* __restrict__ out) {
    __shared__ v2f xs[CT * XSTRIDE];    // 50,944 B  (c-major, batch-paired x)
    __shared__ v2f rs[CT * RSTRIDE];    // 25,344 B  (c-major, dn-paired R)

    const int bx = blockIdx.x;          // 2048 blocks
    const int ct = bx & 15;             // 16 channel tiles of 32
    const int bp = bx >> 4;             // 0..127 batch pairs
    const int c0 = ct * CT;
    const int b0 = bp * 2;
    const int t  = threadIdx.x;

    const float* xb = x + (size_t)b0 * Ns * Cc + c0;
    const v2f*  Rbv = (const v2f*)R + c0;          // pair units, channel offset
    for (int i = t; i < Ns * CT; i += CONV_THREADS) {
        int pq = i >> 5;
        int cc = i & (CT - 1);
        v2f v;
        v.x = xb[pq * Cc + cc];
        v.y = xb[(size_t)Ns * Cc + pq * Cc + cc];
        xs[cc * XSTRIDE + pq] = v;
    }
    for (int i = t; i < 98 * CT; i += CONV_THREADS) {
        int j  = i >> 5;
        int cc = i & (CT - 1);
        rs[cc * RSTRIDE + j] = Rbv[j * Cc + cc];
    }
    __syncthreads();

    const int c = t & (CT - 1);
    const int m = t >> 5;               // 0..13

    v2f acc[14];
    #pragma unroll
    for (int n = 0; n < 14; ++n) acc[n] = 0.0f;

    const unsigned xs_c = (unsigned)(size_t)&xs[c * XSTRIDE];
    const unsigned rs_c = (unsigned)(size_t)&rs[c * RSTRIDE];

    // prologue: bank A loads for p=0 (dm = m)
    {
        unsigned xa = xs_c;
        unsigned ra = rs_c + (unsigned)(m * 56);
        asm volatile(LOADS_TO_A("%0", "%1")
                     : : "v"(xa), "v"(ra) : "memory", CLOB);
    }

    int dm = m;
    #pragma unroll 1
    for (int pp = 0; pp < 7; ++pp) {
        int p = 2 * pp;
        // compute p (bank A); load p+1 into bank B
        dm = (dm == 0) ? 13 : (dm - 1);                 // dm for p+1
        unsigned xb1 = xs_c + (unsigned)((p + 1) * 112);
        unsigned rb1 = rs_c + (unsigned)(dm * 56);
        asm volatile(
            "s_waitcnt lgkmcnt(0)\n\t"
            LOADS_TO_B("%14", "%15")
            FMAS_A
            : ACCS : "v"(xb1), "v"(rb1) : "memory", CLOB);

        // compute p+1 (bank B); load p+2 into bank A (p=14 wraps to 0, dead)
        dm = (dm == 0) ? 13 : (dm - 1);                 // dm for p+2
        int p2 = (p + 2 == 14) ? 0 : (p + 2);
        unsigned xa2 = xs_c + (unsigned)(p2 * 112);
        unsigned ra2 = rs_c + (unsigned)(dm * 56);
        asm volatile(
            "s_waitcnt lgkmcnt(0)\n\t"
            LOADS_TO_A("%14", "%15")
            FMAS_B
            : ACCS : "v"(xa2), "v"(ra2) : "memory", CLOB);
    }
    // drain the final (dead) bank-A loads before wave exit
    asm volatile("s_waitcnt lgkmcnt(0)" ::: "memory");

    float* o0 = out + ((size_t)b0 * Ns + m * 14) * Cc + c0 + c;
    float* o1 = o0 + (size_t)Ns * Cc;
    #pragma unroll
    for (int n = 0; n < 14; ++n) {
        o0[n * Cc] = acc[n].x;
        o1[n * Cc] = acc[n].y;
    }
}

extern "C" void kernel_launch(void* const* d_in, const int* in_sizes, int n_in,
                              void* d_out, int out_size, void* d_ws, size_t ws_size,
                              hipStream_t stream) {
    const float* x  = (const float*)d_in[0];
    const float* cw = (const float*)d_in[1];
    float* outp = (float*)d_out;
    float* R = (float*)d_ws;                    // 196*512 floats (pair layout)
    float* T = R + (size_t)Ns * Cc;             // 14*14*512*2 floats

    prep_a_kernel<<<392, 256, 0, stream>>>(cw, T);
    prep_b_kernel<<<392, 256, 0, stream>>>(T, R);
    conv_kernel<<<128 * 16, CONV_THREADS, 0, stream>>>(x, R, outp);
}

// Round 7
// 286.704 us; speedup vs baseline: 1.4110x; 1.4110x over previous
//
#include <hip/hip_runtime.h>

// GlobalFilter: y = irfft2(rfft2(x, ortho) * W, ortho)  ==  per-channel 14x14
// circular convolution with kernel R_c = (1/196) * Re(IFFT2(Wext_c)).
//
// x: (256, 196, 512) fp32, W: (14, 8, 512, 2) fp32, out: (256, 196, 512) fp32.
//
// ws layout: R  at offset 0            : 196*512 floats  (401,408 B)
//               *** pair layout ***: R[((dm*7 + dn/2)*512 + c)*2 + (dn&1)]
//            T  at offset 196*512      : 14*14*512*2 floats (802,816 B)
//
// Round-7: revert to the R5 single-bank asm structure (165 us) and change
// ONE thing: graduated counted lgkmcnt waits inside the per-p asm block.
// R5 drained all 21 loads (lgkmcnt(0), ~250 cy serial per p) before any FMA.
// DS ops complete in order, so: issue 7 R reads then 14 x reads; wait
// lgkmcnt(13) (= all R + x0) -> column q=0 FMAs; lgkmcnt(12) -> q=1; ...
// lgkmcnt(0) -> q=13.  Column q: acc[(q+dn)%14] += x_q * r[dn], op_sel
// half-broadcast of the R pair (verified R2/R5).

#define Hs 14
#define Ns 196          // 14*14
#define Cc 512
#define CT 32           // channel tile
#define CONV_THREADS 448

typedef float v2f __attribute__((ext_vector_type(2)));

// ---------------------------------------------------------------------------
// Prep stage A (unchanged)
// ---------------------------------------------------------------------------
__global__ __launch_bounds__(256) void prep_a_kernel(const float* __restrict__ cw,
                                                     float* __restrict__ T) {
    __shared__ float cs[14], sn[14];
    if (threadIdx.x < 14) {
        float ang = (float)threadIdx.x * 0.44879895051282760549f;  // 2*pi/14
        cs[threadIdx.x] = cosf(ang);
        sn[threadIdx.x] = sinf(ang);
    }
    __syncthreads();

    int gid = blockIdx.x * 256 + threadIdx.x;   // 14*14*512
    int c = gid & 511;
    int s = gid >> 9;          // h*14 + dn
    int h = s / 14;
    int dn = s % 14;
    int h2 = (h == 0) ? 0 : (14 - h);

    float Tr = 0.0f, Ti = 0.0f;
    int k = 0;
    #pragma unroll
    for (int w = 0; w < 8; ++w) {
        const float* p = cw + (size_t)(((h * 8 + w) * 512 + c) * 2);
        float Wr = p[0], Wi = p[1];
        Tr += Wr * cs[k] - Wi * sn[k];
        Ti += Wr * sn[k] + Wi * cs[k];
        k += dn; if (k >= 14) k -= 14;
    }
    int k2 = dn; if (k2 >= 14) k2 -= 14;
    #pragma unroll
    for (int w = 1; w < 7; ++w) {
        const float* p = cw + (size_t)(((h2 * 8 + w) * 512 + c) * 2);
        float Wr = p[0], Wi = p[1];
        Tr += Wr * cs[k2] - Wi * sn[k2];
        Ti -= Wr * sn[k2] + Wi * cs[k2];
        k2 += dn; if (k2 >= 14) k2 -= 14;
    }
    float* o = T + (size_t)(s * 512 + c) * 2;
    o[0] = Tr;
    o[1] = Ti;
}

// ---------------------------------------------------------------------------
// Prep stage B (unchanged; writes R in dn-PAIR layout)
// ---------------------------------------------------------------------------
__global__ __launch_bounds__(256) void prep_b_kernel(const float* __restrict__ T,
                                                     float* __restrict__ R) {
    __shared__ float cs[14], sn[14];
    if (threadIdx.x < 14) {
        float ang = (float)threadIdx.x * 0.44879895051282760549f;  // 2*pi/14
        cs[threadIdx.x] = cosf(ang);
        sn[threadIdx.x] = sinf(ang);
    }
    __syncthreads();

    int gid = blockIdx.x * 256 + threadIdx.x;   // 196*512
    int c = gid & 511;
    int s = gid >> 9;          // dm*14 + dn
    int dm = s / 14;
    int dn = s % 14;

    float acc = 0.0f;
    int kh = 0;
    #pragma unroll
    for (int h = 0; h < 14; ++h) {
        const float* p = T + (size_t)(((h * 14 + dn) * 512 + c) * 2);
        acc += p[0] * cs[kh] - p[1] * sn[kh];
        kh += dm; if (kh >= 14) kh -= 14;
    }
    R[(size_t)(((dm * 7 + (dn >> 1)) * 512 + c) * 2 + (dn & 1))] = acc * (1.0f / 196.0f);
}

// ---------------------------------------------------------------------------
// Conv kernel.  Per p, ONE asm block:
//    7x ds_read_b64 R pairs -> v[68..81]  (row dm)
//   14x ds_read_b64 x       -> v[40..67]  (row p)
//   then 14 columns, each: s_waitcnt lgkmcnt(13-q); 14 v_pk_fma_f32
//   column q: acc[(q+dn)%14] += x_q * r[dn]
//     dn even -> pair.lo both lanes (SEL_E), dn odd -> pair.hi (SEL_O)
// ---------------------------------------------------------------------------
#define SEL_E "op_sel:[0,0,0] op_sel_hi:[1,0,1]"
#define SEL_O "op_sel:[0,1,0] op_sel_hi:[1,1,1]"

// one column: fixed x register X, R pairs v[68:69]..v[80:81], rotated accs
#define COL(X, a0,a1,a2,a3,a4,a5,a6,a7,a8,a9,aA,aB,aC,aD) \
  "v_pk_fma_f32 %" #a0 ", " X ", v[68:69], %" #a0 " " SEL_E "\n\t" \
  "v_pk_fma_f32 %" #a1 ", " X ", v[68:69], %" #a1 " " SEL_O "\n\t" \
  "v_pk_fma_f32 %" #a2 ", " X ", v[70:71], %" #a2 " " SEL_E "\n\t" \
  "v_pk_fma_f32 %" #a3 ", " X ", v[70:71], %" #a3 " " SEL_O "\n\t" \
  "v_pk_fma_f32 %" #a4 ", " X ", v[72:73], %" #a4 " " SEL_E "\n\t" \
  "v_pk_fma_f32 %" #a5 ", " X ", v[72:73], %" #a5 " " SEL_O "\n\t" \
  "v_pk_fma_f32 %" #a6 ", " X ", v[74:75], %" #a6 " " SEL_E "\n\t" \
  "v_pk_fma_f32 %" #a7 ", " X ", v[74:75], %" #a7 " " SEL_O "\n\t" \
  "v_pk_fma_f32 %" #a8 ", " X ", v[76:77], %" #a8 " " SEL_E "\n\t" \
  "v_pk_fma_f32 %" #a9 ", " X ", v[76:77], %" #a9 " " SEL_O "\n\t" \
  "v_pk_fma_f32 %" #aA ", " X ", v[78:79], %" #aA " " SEL_E "\n\t" \
  "v_pk_fma_f32 %" #aB ", " X ", v[78:79], %" #aB " " SEL_O "\n\t" \
  "v_pk_fma_f32 %" #aC ", " X ", v[80:81], %" #aC " " SEL_E "\n\t" \
  "v_pk_fma_f32 %" #aD ", " X ", v[80:81], %" #aD " " SEL_O "\n\t"

#define XSTRIDE 199   // v2f units, c-major row stride for xs
#define RSTRIDE 99    // v2f units, c-major row stride for rs

__global__ __launch_bounds__(CONV_THREADS, 2) void conv_kernel(
        const float* __restrict__ x,
        const float* __restrict__ R,
        float* __restrict__ out) {
    __shared__ v2f xs[CT * XSTRIDE];    // 50,944 B  (c-major, batch-paired x)
    __shared__ v2f rs[CT * RSTRIDE];    // 25,344 B  (c-major, dn-paired R)

    const int bx = blockIdx.x;          // 2048 blocks
    const int ct = bx & 15;             // 16 channel tiles of 32
    const int bp = bx >> 4;             // 0..127 batch pairs
    const int c0 = ct * CT;
    const int b0 = bp * 2;
    const int t  = threadIdx.x;

    const float* xb = x + (size_t)b0 * Ns * Cc + c0;
    const v2f*  Rbv = (const v2f*)R + c0;          // pair units, channel offset
    for (int i = t; i < Ns * CT; i += CONV_THREADS) {
        int pq = i >> 5;
        int cc = i & (CT - 1);
        v2f v;
        v.x = xb[pq * Cc + cc];
        v.y = xb[(size_t)Ns * Cc + pq * Cc + cc];
        xs[cc * XSTRIDE + pq] = v;
    }
    for (int i = t; i < 98 * CT; i += CONV_THREADS) {
        int j  = i >> 5;
        int cc = i & (CT - 1);
        rs[cc * RSTRIDE + j] = Rbv[j * Cc + cc];
    }
    __syncthreads();

    const int c = t & (CT - 1);
    const int m = t >> 5;               // 0..13

    v2f acc[14];
    #pragma unroll
    for (int n = 0; n < 14; ++n) acc[n] = 0.0f;

    const unsigned xs_c = (unsigned)(size_t)&xs[c * XSTRIDE];
    const unsigned rs_c = (unsigned)(size_t)&rs[c * RSTRIDE];

    int dm = m;
    #pragma unroll 1
    for (int p = 0; p < 14; ++p) {
        unsigned xa = xs_c + (unsigned)(p * 14 * 8);   // row p of x (14 v2f)
        unsigned ra = rs_c + (unsigned)(dm * 7 * 8);   // row dm of R (7 pairs)
        asm volatile(
            // R pairs first (7), then x (14) — DS completes in order
            "ds_read_b64 v[68:69], %15\n\t"
            "ds_read_b64 v[70:71], %15 offset:8\n\t"
            "ds_read_b64 v[72:73], %15 offset:16\n\t"
            "ds_read_b64 v[74:75], %15 offset:24\n\t"
            "ds_read_b64 v[76:77], %15 offset:32\n\t"
            "ds_read_b64 v[78:79], %15 offset:40\n\t"
            "ds_read_b64 v[80:81], %15 offset:48\n\t"
            "ds_read_b64 v[40:41], %14\n\t"
            "ds_read_b64 v[42:43], %14 offset:8\n\t"
            "ds_read_b64 v[44:45], %14 offset:16\n\t"
            "ds_read_b64 v[46:47], %14 offset:24\n\t"
            "ds_read_b64 v[48:49], %14 offset:32\n\t"
            "ds_read_b64 v[50:51], %14 offset:40\n\t"
            "ds_read_b64 v[52:53], %14 offset:48\n\t"
            "ds_read_b64 v[54:55], %14 offset:56\n\t"
            "ds_read_b64 v[56:57], %14 offset:64\n\t"
            "ds_read_b64 v[58:59], %14 offset:72\n\t"
            "ds_read_b64 v[60:61], %14 offset:80\n\t"
            "ds_read_b64 v[62:63], %14 offset:88\n\t"
            "ds_read_b64 v[64:65], %14 offset:96\n\t"
            "ds_read_b64 v[66:67], %14 offset:104\n\t"
            "s_waitcnt lgkmcnt(13)\n\t"   // 7 R + x0 landed
            COL("v[40:41]",  0,1,2,3,4,5,6,7,8,9,10,11,12,13)
            "s_waitcnt lgkmcnt(12)\n\t"
            COL("v[42:43]",  1,2,3,4,5,6,7,8,9,10,11,12,13,0)
            "s_waitcnt lgkmcnt(11)\n\t"
            COL("v[44:45]",  2,3,4,5,6,7,8,9,10,11,12,13,0,1)
            "s_waitcnt lgkmcnt(10)\n\t"
            COL("v[46:47]",  3,4,5,6,7,8,9,10,11,12,13,0,1,2)
            "s_waitcnt lgkmcnt(9)\n\t"
            COL("v[48:49]",  4,5,6,7,8,9,10,11,12,13,0,1,2,3)
            "s_waitcnt lgkmcnt(8)\n\t"
            COL("v[50:51]",  5,6,7,8,9,10,11,12,13,0,1,2,3,4)
            "s_waitcnt lgkmcnt(7)\n\t"
            COL("v[52:53]",  6,7,8,9,10,11,12,13,0,1,2,3,4,5)
            "s_waitcnt lgkmcnt(6)\n\t"
            COL("v[54:55]",  7,8,9,10,11,12,13,0,1,2,3,4,5,6)
            "s_waitcnt lgkmcnt(5)\n\t"
            COL("v[56:57]",  8,9,10,11,12,13,0,1,2,3,4,5,6,7)
            "s_waitcnt lgkmcnt(4)\n\t"
            COL("v[58:59]",  9,10,11,12,13,0,1,2,3,4,5,6,7,8)
            "s_waitcnt lgkmcnt(3)\n\t"
            COL("v[60:61]",  10,11,12,13,0,1,2,3,4,5,6,7,8,9)
            "s_waitcnt lgkmcnt(2)\n\t"
            COL("v[62:63]",  11,12,13,0,1,2,3,4,5,6,7,8,9,10)
            "s_waitcnt lgkmcnt(1)\n\t"
            COL("v[64:65]",  12,13,0,1,2,3,4,5,6,7,8,9,10,11)
            "s_waitcnt lgkmcnt(0)\n\t"
            COL("v[66:67]",  13,0,1,2,3,4,5,6,7,8,9,10,11,12)
            : "+v"(acc[0]), "+v"(acc[1]), "+v"(acc[2]), "+v"(acc[3]),
              "+v"(acc[4]), "+v"(acc[5]), "+v"(acc[6]), "+v"(acc[7]),
              "+v"(acc[8]), "+v"(acc[9]), "+v"(acc[10]), "+v"(acc[11]),
              "+v"(acc[12]), "+v"(acc[13])
            : "v"(xa), "v"(ra)
            : "memory",
              "v40","v41","v42","v43","v44","v45","v46","v47",
              "v48","v49","v50","v51","v52","v53","v54","v55",
              "v56","v57","v58","v59","v60","v61","v62","v63",
              "v64","v65","v66","v67","v68","v69","v70","v71",
              "v72","v73","v74","v75","v76","v77","v78","v79",
              "v80","v81");
        dm = (dm == 0) ? 13 : (dm - 1);
    }

    float* o0 = out + ((size_t)b0 * Ns + m * 14) * Cc + c0 + c;
    float* o1 = o0 + (size_t)Ns * Cc;
    #pragma unroll
    for (int n = 0; n < 14; ++n) {
        o0[n * Cc] = acc[n].x;
        o1[n * Cc] = acc[n].y;
    }
}

extern "C" void kernel_launch(void* const* d_in, const int* in_sizes, int n_in,
                              void* d_out, int out_size, void* d_ws, size_t ws_size,
                              hipStream_t stream) {
    const float* x  = (const float*)d_in[0];
    const float* cw = (const float*)d_in[1];
    float* outp = (float*)d_out;
    float* R = (float*)d_ws;                    // 196*512 floats (pair layout)
    float* T = R + (size_t)Ns * Cc;             // 14*14*512*2 floats

    prep_a_kernel<<<392, 256, 0, stream>>>(cw, T);
    prep_b_kernel<<<392, 256, 0, stream>>>(T, R);
    conv_kernel<<<128 * 16, CONV_THREADS, 0, stream>>>(x, R, outp);
}

// Round 8
// 263.817 us; speedup vs baseline: 1.5334x; 1.0868x over previous
//
#include <hip/hip_runtime.h>

// GlobalFilter: y = irfft2(rfft2(x, ortho) * W, ortho)  ==  per-channel 14x14
// circular convolution with kernel R_c = (1/196) * Re(IFFT2(Wext_c)).
//
// x: (256, 196, 512) fp32, W: (14, 8, 512, 2) fp32, out: (256, 196, 512) fp32.
//
// Round-8: switch the inner math to v_dot2_f32_f16 (2 f16 MACs/lane/cycle,
// f32 accumulate = 2x the fp32-vector rate). R7's accounting showed the
// kernel was FMA-floor-bound: v_pk_fma_f32 is 4 cy/instr (2 FLOP/lane/cy),
// floor 64 us; dot2 halves that AND halves LDS bytes (fp16 operands).
// Precision path identical to R3 (fp16 inputs, f32 accum; passed 9.77e-4).
//
// ws: R   (fp32, plain [dm*14+dn][c])  at 0       : 196*512 floats
//     T   (complex fp32)               at 196*512 : 14*14*512*2 floats
//     R16 (fp16 pair-table, overwrites T after prep_b):
//         word[s=dm*14+w][c]: w<7  -> E_w = {R[dm,2w],   R[dm,(2w+13)%14]}
//                             w>=7 -> O_{w-7} = {R[dm,2k+1], R[dm,2k]}

#define Ns 196          // 14*14
#define Cc 512
#define CT 32           // channel tile
#define CONV_THREADS 448  // 32 c x 14 m, ONE batch per block

typedef _Float16 h2 __attribute__((ext_vector_type(2)));
union U32H2 { unsigned u; h2 h; };

static __device__ inline float fdot2(unsigned a, unsigned b, float c) {
#if __has_builtin(__builtin_amdgcn_fdot2)
    U32H2 ua; ua.u = a;
    U32H2 ub; ub.u = b;
    return __builtin_amdgcn_fdot2(ua.h, ub.h, c, false);
#else
    float d = c;
    asm("v_dot2_f32_f16 %0, %1, %2, %0" : "+v"(d) : "v"(a), "v"(b));
    return d;
#endif
}

// ---------------------------------------------------------------------------
// Prep stage A:  T[h][dn][c] = sum_w Wext[h,w,c] z^{w*dn}   (unchanged)
// ---------------------------------------------------------------------------
__global__ __launch_bounds__(256) void prep_a_kernel(const float* __restrict__ cw,
                                                     float* __restrict__ T) {
    __shared__ float cs[14], sn[14];
    if (threadIdx.x < 14) {
        float ang = (float)threadIdx.x * 0.44879895051282760549f;  // 2*pi/14
        cs[threadIdx.x] = cosf(ang);
        sn[threadIdx.x] = sinf(ang);
    }
    __syncthreads();

    int gid = blockIdx.x * 256 + threadIdx.x;   // 14*14*512
    int c = gid & 511;
    int s = gid >> 9;          // h*14 + dn
    int h = s / 14;
    int dn = s % 14;
    int h2v = (h == 0) ? 0 : (14 - h);

    float Tr = 0.0f, Ti = 0.0f;
    int k = 0;
    #pragma unroll
    for (int w = 0; w < 8; ++w) {
        const float* p = cw + (size_t)(((h * 8 + w) * 512 + c) * 2);
        float Wr = p[0], Wi = p[1];
        Tr += Wr * cs[k] - Wi * sn[k];
        Ti += Wr * sn[k] + Wi * cs[k];
        k += dn; if (k >= 14) k -= 14;
    }
    int k2 = dn; if (k2 >= 14) k2 -= 14;
    #pragma unroll
    for (int w = 1; w < 7; ++w) {
        const float* p = cw + (size_t)(((h2v * 8 + w) * 512 + c) * 2);
        float Wr = p[0], Wi = p[1];
        Tr += Wr * cs[k2] - Wi * sn[k2];
        Ti -= Wr * sn[k2] + Wi * cs[k2];
        k2 += dn; if (k2 >= 14) k2 -= 14;
    }
    float* o = T + (size_t)(s * 512 + c) * 2;
    o[0] = Tr;
    o[1] = Ti;
}

// ---------------------------------------------------------------------------
// Prep stage B (PLAIN layout):  R[(dm*14+dn)*512 + c]
// ---------------------------------------------------------------------------
__global__ __launch_bounds__(256) void prep_b_kernel(const float* __restrict__ T,
                                                     float* __restrict__ R) {
    __shared__ float cs[14], sn[14];
    if (threadIdx.x < 14) {
        float ang = (float)threadIdx.x * 0.44879895051282760549f;  // 2*pi/14
        cs[threadIdx.x] = cosf(ang);
        sn[threadIdx.x] = sinf(ang);
    }
    __syncthreads();

    int gid = blockIdx.x * 256 + threadIdx.x;   // 196*512
    int c = gid & 511;
    int s = gid >> 9;          // dm*14 + dn
    int dm = s / 14;
    int dn = s % 14;

    float acc = 0.0f;
    int kh = 0;
    #pragma unroll
    for (int h = 0; h < 14; ++h) {
        const float* p = T + (size_t)(((h * 14 + dn) * 512 + c) * 2);
        acc += p[0] * cs[kh] - p[1] * sn[kh];
        kh += dm; if (kh >= 14) kh -= 14;
    }
    R[s * 512 + c] = acc * (1.0f / 196.0f);
}

// ---------------------------------------------------------------------------
// Prep stage C: build the fp16 dot2 pair-table R16 (into T's storage).
//   word[s = dm*14 + w][c]:
//     w in 0..6  : {R[dm, 2w],     R[dm, (2w+13)%14]}   (E-words)
//     w in 7..13 : {R[dm, 2(w-7)+1], R[dm, 2(w-7)]}     (O-words)
// ---------------------------------------------------------------------------
__global__ __launch_bounds__(256) void prep_c_kernel(const float* __restrict__ R,
                                                     unsigned* __restrict__ R16) {
    int gid = blockIdx.x * 256 + threadIdx.x;   // 196*512
    int c = gid & 511;
    int s = gid >> 9;          // dm*14 + w
    int dm = s / 14;
    int w = s % 14;
    int d0, d1;
    if (w < 7) { d0 = 2 * w;           d1 = (2 * w + 13) % 14; }
    else       { int k = w - 7; d0 = 2 * k + 1; d1 = 2 * k; }
    float v0 = R[(dm * 14 + d0) * 512 + c];
    float v1 = R[(dm * 14 + d1) * 512 + c];
    U32H2 u; u.h = h2{(_Float16)v0, (_Float16)v1};
    R16[s * 512 + c] = u.u;
}

// ---------------------------------------------------------------------------
// Conv: block = (batch b, 32-channel tile). 448 threads: c = t&31, m = t>>5.
//   acc[n] (f32) over p: for q-pairs j: acc[n] += dot2(x_pair[j], Rword)
//     n even: word k = (n/2 - j) mod 7         (E)
//     n odd : word 7 + ((n-1)/2 - j) mod 7     (O)
// LDS [row][33 c] layout: all b32 reads, consecutive addresses across lanes
// (conflict-free, half-wave broadcast). LDS = 38.8 KB -> 4 blocks/CU.
// ---------------------------------------------------------------------------
__global__ __launch_bounds__(CONV_THREADS, 8) void conv_kernel(
        const float* __restrict__ x,
        const unsigned* __restrict__ R16,
        float* __restrict__ out) {
    __shared__ unsigned xs[98 * 33];    // x pair-words: [e = pq/2][33 c] 12,936 B
    __shared__ unsigned rs[196 * 33];   // R16 words:    [s = dm*14+w][33 c] 25,872 B

    const int bx = blockIdx.x;          // 4096 blocks = 256 b x 16 ct
    const int ct = bx & 15;
    const int b  = bx >> 4;
    const int c0 = ct * CT;
    const int t  = threadIdx.x;

    const float* xg = x + (size_t)b * Ns * Cc + c0;
    for (int i = t; i < 98 * CT; i += CONV_THREADS) {
        int e  = i >> 5;
        int cc = i & 31;
        float f0 = xg[(2 * e)     * Cc + cc];
        float f1 = xg[(2 * e + 1) * Cc + cc];
        U32H2 u; u.h = h2{(_Float16)f0, (_Float16)f1};
        xs[e * 33 + cc] = u.u;
    }
    const unsigned* rg = R16 + c0;
    for (int i = t; i < 196 * CT; i += CONV_THREADS) {
        int s  = i >> 5;
        int cc = i & 31;
        rs[s * 33 + cc] = rg[s * Cc + cc];
    }
    __syncthreads();

    const int c = t & 31;
    const int m = t >> 5;               // 0..13

    float acc[14];
    #pragma unroll
    for (int n = 0; n < 14; ++n) acc[n] = 0.0f;

    #pragma unroll 1
    for (int p = 0; p < 14; ++p) {
        int dm = m - p; if (dm < 0) dm += 14;
        const unsigned* xr = xs + p  * 7  * 33 + c;
        const unsigned* rr = rs + dm * 14 * 33 + c;

        unsigned xw[7];
        #pragma unroll
        for (int j = 0; j < 7; ++j) xw[j] = xr[j * 33];
        unsigned rw[14];
        #pragma unroll
        for (int w = 0; w < 14; ++w) rw[w] = rr[w * 33];

        #pragma unroll
        for (int n = 0; n < 14; ++n) {
            #pragma unroll
            for (int j = 0; j < 7; ++j) {
                int w;
                if ((n & 1) == 0) w = ((n >> 1) - j + 7) % 7;
                else              w = 7 + ((((n - 1) >> 1) - j + 7) % 7);
                acc[n] = fdot2(xw[j], rw[w], acc[n]);
            }
        }
    }

    float* o = out + ((size_t)b * Ns + m * 14) * Cc + c0 + c;
    #pragma unroll
    for (int n = 0; n < 14; ++n) o[n * Cc] = acc[n];
}

extern "C" void kernel_launch(void* const* d_in, const int* in_sizes, int n_in,
                              void* d_out, int out_size, void* d_ws, size_t ws_size,
                              hipStream_t stream) {
    const float* x  = (const float*)d_in[0];
    const float* cw = (const float*)d_in[1];
    float* outp = (float*)d_out;
    float* R = (float*)d_ws;                        // 196*512 floats (plain)
    float* T = R + (size_t)Ns * Cc;                 // 14*14*512*2 floats
    unsigned* R16 = (unsigned*)T;                   // overwrites T after prep_b

    prep_a_kernel<<<392, 256, 0, stream>>>(cw, T);
    prep_b_kernel<<<392, 256, 0, stream>>>(T, R);
    prep_c_kernel<<<392, 256, 0, stream>>>(R, R16);
    conv_kernel<<<256 * 16, CONV_THREADS, 0, stream>>>(x, R16, outp);
}